// Round 19
// baseline (67.659 us; speedup 1.0000x reference)
//
#include <hip/hip_runtime.h>
#include <stdint.h>

typedef __attribute__((ext_vector_type(4))) float f32x4;
typedef __attribute__((ext_vector_type(8))) short short8;
typedef __attribute__((ext_vector_type(8))) int int8v;

#define NROWS 8192
#define SCALE1 0x7F7F7F7F  // 4x E8M0 bytes encoding 2^0 = 1.0

static __device__ __forceinline__ unsigned int f2bf(float f) {
  unsigned int u = __float_as_uint(f);
  return (u + 0x7fffu + ((u >> 16) & 1u)) >> 16;  // RNE
}
static __device__ __forceinline__ float bf2f(unsigned int h) {
  return __uint_as_float(h << 16);
}
static __device__ __forceinline__ float fast_exp2(float x) {
#if __has_builtin(__builtin_amdgcn_exp2f)
  return __builtin_amdgcn_exp2f(x);
#else
  float r;
  asm("v_exp_f32 %0, %1" : "=v"(r) : "v"(x));
  return r;
#endif
}
static __device__ __forceinline__ float fast_expm1(float x) {
  return fast_exp2(x * 1.4426950408889634f) - 1.0f;
}
// f32 -> OCP e4m3fn byte
static __device__ __forceinline__ unsigned f2fp8(float v) {
#if __has_builtin(__builtin_amdgcn_cvt_pk_fp8_f32)
  return (unsigned)__builtin_amdgcn_cvt_pk_fp8_f32(v, v, 0, false) & 0xFFu;
#else
  float a = fabsf(v);
  unsigned sgn = v < 0.f ? 0x80u : 0u;
  if (a > 448.f) a = 448.f;
  if (a < 0.015625f) {
    int q = (int)(a * 512.0f + 0.5f);
    return sgn | (unsigned)q;
  }
  int ex;
  float mant = frexpf(a, &ex);
  int e = ex + 6;
  int m = (int)(mant * 16.0f + 0.5f) - 8;
  if (m == 8) { m = 0; ++e; }
  if (e > 15) { e = 15; m = 7; }
  return sgn | (unsigned)(e << 3) | (unsigned)m;
#endif
}
// OCP e4m3fn byte -> f32
static __device__ __forceinline__ float fp8d(unsigned b) {
  unsigned e = (b >> 3) & 15u, m = b & 7u;
  float v = (e == 0) ? (float)m * 0.001953125f
                     : __uint_as_float(((e + 120u) << 23) | (m << 20));
  return (b & 0x80u) ? -v : v;
}

// hs-fp8 layout: rows of 128 B; 16B chunk c stored at position c ^ (row&7).
// Pre-swizzled global + linear global_load_lds DMA + per-lane swizzled read
// addresses (m201 both-sides pattern). Lane fragment for 16x16x128 MFMA:
// row = l&15, k-bytes = logical chunks {2lh, 2lh+1}.
// W-bf16 layout: per 256B row r, f32x4-chunk q at byte
// r*256 + (((q>>1)^(r&7))<<4 | (q&1)<<3)   (proj fragment swizzle).

// ---------------------------------------------------------------------------
// Kernel 0 (r19): one-time W1/W2 f32 -> bf16 pre-swizzled conversion.
// 16 blocks x 256 thr; thread c converts one f32x4 of each W.
// ---------------------------------------------------------------------------
__global__ __launch_bounds__(256) void wconv_kernel(
    const float* __restrict__ w1g, const float* __restrict__ w2g,
    unsigned short* __restrict__ w1b, unsigned short* __restrict__ w2b) {
  const int c = blockIdx.x * 256 + threadIdx.x;  // 0..4095
  const int r = c >> 5, q = c & 31;
  const int off = r * 256 + ((((q >> 1) ^ (r & 7)) << 4) | ((q & 1) << 3));
  f32x4 va = *(const f32x4*)&w1g[c * 4];
  f32x4 vb = *(const f32x4*)&w2g[c * 4];
  uint2 pa, pb;
  pa.x = f2bf(va.x) | (f2bf(va.y) << 16);
  pa.y = f2bf(va.z) | (f2bf(va.w) << 16);
  pb.x = f2bf(vb.x) | (f2bf(vb.y) << 16);
  pb.y = f2bf(vb.z) | (f2bf(vb.w) << 16);
  *(uint2*)((char*)w1b + off) = pa;
  *(uint2*)((char*)w2b + off) = pb;
}

// ---------------------------------------------------------------------------
// Kernel 1: projection fc2(elu(fc1(z))) + L2-normalize, bf16 MFMA + f32
// epilogue; fp8 e4m3 output rows pre-scaled by sqrt(2*log2 e).
// r19: W1/W2 arrive pre-converted/pre-swizzled -> DMA'd into LDS via
// global_load_lds (removes 128KB f32 reads + 32K converts per block).
// ---------------------------------------------------------------------------
__global__ __launch_bounds__(256) void proj_kernel(
    const float* __restrict__ z1, const float* __restrict__ z2,
    const unsigned short* __restrict__ w1b, const unsigned short* __restrict__ w2b,
    const float* __restrict__ b1g, const float* __restrict__ b2g,
    unsigned char* __restrict__ hs1, unsigned char* __restrict__ hs2) {
  __shared__ __align__(16) unsigned short W1[128 * 128];
  __shared__ __align__(16) unsigned short W2[128 * 128];
  __shared__ unsigned short X[64 * 128];
  const int tid = threadIdx.x;
  const int w = tid >> 6, l = tid & 63, l16 = l & 15, lh = l >> 4;
  const int zi = blockIdx.x >> 7, rb = blockIdx.x & 127;
  const float* zg = (zi ? z2 : z1) + (size_t)rb * 64 * 128;
  unsigned char* outp = (zi ? hs2 : hs1) + (size_t)rb * 64 * 128;

  // DMA pre-swizzled W1/W2 (32KB each) straight into LDS
#pragma unroll
  for (int s = 0; s < 8; ++s) {
    const char* s1 = (const char*)w1b + s * 4096 + tid * 16;
    const char* s2 = (const char*)w2b + s * 4096 + tid * 16;
    char* d1 = (char*)W1 + s * 4096 + w * 1024;  // wave-uniform base
    char* d2 = (char*)W2 + s * 4096 + w * 1024;
    __builtin_amdgcn_global_load_lds(
        (const __attribute__((address_space(1))) void*)s1,
        (__attribute__((address_space(3))) void*)d1, 16, 0, 0);
    __builtin_amdgcn_global_load_lds(
        (const __attribute__((address_space(1))) void*)s2,
        (__attribute__((address_space(3))) void*)d2, 16, 0, 0);
  }

  float bias1[8], bias2[8];
#pragma unroll
  for (int nf = 0; nf < 8; ++nf) {
    bias1[nf] = b1g[nf * 16 + l16];
    bias2[nf] = b2g[nf * 16 + l16];
  }

#pragma unroll
  for (int t = 0; t < 8; ++t) {
    int c = tid + t * 256;
    int r = c >> 5, q = c & 31;
    int off = r * 256 + ((((q >> 1) ^ (r & 7)) << 4) | ((q & 1) << 3));
    f32x4 v = *(const f32x4*)&zg[c * 4];
    uint2 p;
    p.x = f2bf(v.x) | (f2bf(v.y) << 16);
    p.y = f2bf(v.z) | (f2bf(v.w) << 16);
    *(uint2*)((char*)X + off) = p;
  }
  __syncthreads();  // drains vmcnt (W DMA) + lgkm (X writes)

  const f32x4 ZERO = {0.f, 0.f, 0.f, 0.f};
  const int arow = w * 16 + l16;

  short8 a1[4];
#pragma unroll
  for (int ks = 0; ks < 4; ++ks)
    a1[ks] = *(const short8*)((const char*)X + arow * 256 +
                              ((ks * 64 + lh * 16) ^ ((arow & 7) << 4)));
  f32x4 h[8];
#pragma unroll
  for (int nf = 0; nf < 8; ++nf) {
    const int brow = nf * 16 + l16;
    const char* bp = (const char*)W1 + brow * 256;
    f32x4 c = ZERO;
#pragma unroll
    for (int ks = 0; ks < 4; ++ks) {
      short8 b = *(const short8*)(bp + ((ks * 64 + lh * 16) ^ ((brow & 7) << 4)));
      c = __builtin_amdgcn_mfma_f32_16x16x32_bf16(a1[ks], b, c, 0, 0, 0);
    }
#pragma unroll
    for (int r = 0; r < 4; ++r) {
      float x = c[r] + bias1[nf];
      c[r] = x > 0.f ? x : fast_expm1(x);
    }
    h[nf] = c;
  }
  __syncthreads();

#pragma unroll
  for (int nf = 0; nf < 8; ++nf)
#pragma unroll
    for (int r = 0; r < 4; ++r) {
      int row = w * 16 + lh * 4 + r;
      int c2 = (nf * 16 + l16) * 2;
      int off = row * 256 + ((c2 & ~15) ^ ((row & 7) << 4)) + (c2 & 15);
      *(unsigned short*)((char*)X + off) = (unsigned short)f2bf(h[nf][r]);
    }
  __syncthreads();

  short8 a2[4];
#pragma unroll
  for (int ks = 0; ks < 4; ++ks)
    a2[ks] = *(const short8*)((const char*)X + arow * 256 +
                              ((ks * 64 + lh * 16) ^ ((arow & 7) << 4)));
  f32x4 o[8];
#pragma unroll
  for (int nf = 0; nf < 8; ++nf) {
    const int brow = nf * 16 + l16;
    const char* bp = (const char*)W2 + brow * 256;
    f32x4 c = ZERO;
#pragma unroll
    for (int ks = 0; ks < 4; ++ks) {
      short8 b = *(const short8*)(bp + ((ks * 64 + lh * 16) ^ ((brow & 7) << 4)));
      c = __builtin_amdgcn_mfma_f32_16x16x32_bf16(a2[ks], b, c, 0, 0, 0);
    }
#pragma unroll
    for (int r = 0; r < 4; ++r) c[r] += bias2[nf];
    o[nf] = c;
  }

  float ss[4] = {0.f, 0.f, 0.f, 0.f};
#pragma unroll
  for (int nf = 0; nf < 8; ++nf)
#pragma unroll
    for (int r = 0; r < 4; ++r) ss[r] += o[nf][r] * o[nf][r];
#pragma unroll
  for (int m = 1; m <= 8; m <<= 1)
#pragma unroll
    for (int r = 0; r < 4; ++r) ss[r] += __shfl_xor(ss[r], m, 64);
  float sc[4];
#pragma unroll
  for (int r = 0; r < 4; ++r)
    sc[r] = 1.6986436005760381f / fmaxf(sqrtf(ss[r]), 1e-12f);

#pragma unroll
  for (int nf = 0; nf < 8; ++nf)
#pragma unroll
    for (int r = 0; r < 4; ++r) {
      int row = w * 16 + lh * 4 + r;
      outp[(size_t)row * 128 + ((nf ^ (row & 7)) << 4) + l16] =
          (unsigned char)f2fp8(o[nf][r] * sc[r]);
    }
}

// ---------------------------------------------------------------------------
// Kernel 2: fused Gram + exp2 + row-sum (+ col-sum in pass 2), FP8-MX.
// Base = r15/r18 (46.1us). r19 change: ct tile 64->128 cols (8 cts, Bbuf
// 2x16KB) with ONE barrier per ct — halves barrier/drain events. The inner
// 4-deep group loop is r18's proven body wrapped in `#pragma unroll 1` j-loop
// (r17 lesson: 8-deep unroll spilled; unroll-1 keeps live state identical).
// Config: grid 768 = 3 x 32 rowblocks(256) x 8 cr(1024), 256 thr, (256,3).
// ---------------------------------------------------------------------------
#define EXPBLOCK(G, SLOT)                                             \
  {                                                                   \
    float cs = 0.f;                                                   \
    _Pragma("unroll") for (int mf = 0; mf < 4; ++mf)                  \
        _Pragma("unroll") for (int r = 0; r < 4; ++r) {               \
      float e = fast_exp2(cbuf[SLOT][mf][r]);                         \
      rs[mf][r] += e;                                                 \
      if (do_cs) cs += e;                                             \
    }                                                                 \
    if (do_cs) {                                                      \
      cs += __shfl_xor(cs, 16, 64);                                   \
      cs += __shfl_xor(cs, 32, 64);                                   \
      if (lh == 0) csbuf[cur][w][(G)*16 + l16] = cs;                  \
    }                                                                 \
  }

#define LOADB(P, G)                                                   \
  {                                                                   \
    const char* _bp = (const char*)Bbuf[cur] + ((G)*16 + l16) * 128;  \
    int4 _b0 = *(const int4*)(_bp + koff0);                           \
    int4 _b1 = *(const int4*)(_bp + koff1);                           \
    int8v _v;                                                         \
    _v[0] = _b0.x; _v[1] = _b0.y; _v[2] = _b0.z; _v[3] = _b0.w;       \
    _v[4] = _b1.x; _v[5] = _b1.y; _v[6] = _b1.z; _v[7] = _b1.w;       \
    bvbuf[P] = _v;                                                    \
  }

__global__ __launch_bounds__(256, 3) void gram_kernel(
    const unsigned char* __restrict__ hs1, const unsigned char* __restrict__ hs2,
    float* __restrict__ Rp,     // [24][8192] (pass*8+cr) row-sum partials
    float* __restrict__ R21p) { // [32][8192] col-sum partials (pass 2)
  __shared__ __align__(16) unsigned char Bbuf[2][128 * 128];  // 2 x 16KB
  __shared__ float csbuf[2][4][128];                          // 4KB

  const int tid = threadIdx.x;
  const int w = tid >> 6, l = tid & 63, l16 = l & 15, lh = l >> 4;
  const int pass = blockIdx.x >> 8;
  const int idx = blockIdx.x & 255;
  const int rb = idx >> 3;  // 32 rowblocks of 256 rows
  const int cr = idx & 7;   // 8 col-ranges of 1024 cols

  const unsigned char* Ag = (pass == 1) ? hs2 : hs1;
  const unsigned char* Bg = (pass == 0) ? hs1 : hs2;
  const char* bbase = (const char*)Bg + (size_t)cr * (1024 * 128);
  const bool do_cs = (pass == 2);

  auto STAGE = [&](int buf, int ct) {
#pragma unroll
    for (int s = 0; s < 4; ++s) {
      const char* src = bbase + (size_t)ct * 16384 + s * 4096 + tid * 16;
      char* dst = (char*)Bbuf[buf] + s * 4096 + w * 1024;  // wave-uniform base
      __builtin_amdgcn_global_load_lds(
          (const __attribute__((address_space(1))) void*)src,
          (__attribute__((address_space(3))) void*)dst, 16, 0, 0);
    }
  };

  STAGE(0, 0);

  // per-lane swizzled 16B-chunk offsets for the 2 halves of a 32B fragment
  const int koff0 = ((2 * lh) ^ (l16 & 7)) << 4;
  const int koff1 = ((2 * lh + 1) ^ (l16 & 7)) << 4;

  int8v af[4];  // 64 rows per wave: 32 VGPRs
  {
    const char* abase = (const char*)Ag + ((size_t)rb * 256 + w * 64) * 128;
#pragma unroll
    for (int mf = 0; mf < 4; ++mf) {
      const char* rp = abase + (mf * 16 + l16) * 128;
      int4 x0 = *(const int4*)(rp + koff0);
      int4 x1 = *(const int4*)(rp + koff1);
      int8v v;
      v[0] = x0.x; v[1] = x0.y; v[2] = x0.z; v[3] = x0.w;
      v[4] = x1.x; v[5] = x1.y; v[6] = x1.z; v[7] = x1.w;
      af[mf] = v;
    }
  }

  float rs[4][4];
#pragma unroll
  for (int mf = 0; mf < 4; ++mf)
#pragma unroll
    for (int r = 0; r < 4; ++r) rs[mf][r] = 0.f;
  const f32x4 ZERO = {0.f, 0.f, 0.f, 0.f};

  __syncthreads();  // tile 0 staged

  for (int ct = 0; ct < 8; ++ct) {
    const int cur = ct & 1;
    if (ct + 1 < 8) STAGE(cur ^ 1, ct + 1);
    if (do_cs && w == 0 && ct > 0) {  // flush prev tile's 128 col-sums
#pragma unroll
      for (int h = 0; h < 2; ++h) {
        int col = h * 64 + l;
        float v = (csbuf[cur ^ 1][0][col] + csbuf[cur ^ 1][1][col]) +
                  (csbuf[cur ^ 1][2][col] + csbuf[cur ^ 1][3][col]);
        R21p[(size_t)rb * NROWS + cr * 1024 + (ct - 1) * 128 + col] = v;
      }
    }
    f32x4 cbuf[2][4];
    int8v bvbuf[2];
    LOADB(0, 0)
#pragma unroll 1
    for (int j = 0; j < 2; ++j) {  // NOT unrolled: keeps live state 4-deep
#pragma unroll
      for (int nf = 0; nf < 4; ++nf) {
        if (j * 4 + nf + 1 < 8) LOADB((nf + 1) & 1, j * 4 + nf + 1)
        __builtin_amdgcn_s_setprio(1);
#pragma unroll
        for (int mf = 0; mf < 4; ++mf)  // one MFMA = full K=128 dot
          cbuf[nf & 1][mf] = __builtin_amdgcn_mfma_scale_f32_16x16x128_f8f6f4(
              af[mf], bvbuf[nf & 1], ZERO, 0, 0, 0, SCALE1, 0, SCALE1);
        __builtin_amdgcn_s_setprio(0);
        // deferred exp: previous group's C (parity (nf^1)&1 holds across j)
        if (j > 0 || nf > 0) EXPBLOCK(j * 4 + nf - 1, (nf ^ 1) & 1);
      }
    }
    EXPBLOCK(7, 1);  // last group's exp
    __syncthreads();
  }
  if (do_cs && w == 0) {  // flush last tile (ct=7 -> slot 1)
#pragma unroll
    for (int h = 0; h < 2; ++h) {
      int col = h * 64 + l;
      float v = (csbuf[1][0][col] + csbuf[1][1][col]) +
                (csbuf[1][2][col] + csbuf[1][3][col]);
      R21p[(size_t)rb * NROWS + cr * 1024 + 7 * 128 + col] = v;
    }
  }

  // row-sums: reduce over the 16 col-lanes; C/D row = mf*16 + lh*4 + r [m89]
#pragma unroll
  for (int m = 1; m <= 8; m <<= 1)
#pragma unroll
    for (int mf = 0; mf < 4; ++mf)
#pragma unroll
      for (int r = 0; r < 4; ++r) rs[mf][r] += __shfl_xor(rs[mf][r], m, 64);
  if (l16 == 0) {
    float* base = &Rp[(size_t)(pass * 8 + cr) * NROWS + rb * 256 + w * 64];
#pragma unroll
    for (int mf = 0; mf < 4; ++mf) {
      f32x4 v = {rs[mf][0], rs[mf][1], rs[mf][2], rs[mf][3]};
      *(f32x4*)(base + mf * 16 + lh * 4) = v;
    }
  }
}

// ---------------------------------------------------------------------------
// Kernel 3: merged denom+loss (r15 structure): lane l<24 loads Rp[l][i],
// lanes 24..55 load R21p[l-24][i]; masked wave-reduces give d1,d2.
// ---------------------------------------------------------------------------
__global__ __launch_bounds__(256) void loss_kernel(
    const unsigned char* __restrict__ hs1, const unsigned char* __restrict__ hs2,
    const float* __restrict__ Rp, const float* __restrict__ R21p,
    float* __restrict__ partial) {
  const int tid = threadIdx.x;
  const int l = tid & 63;
  const int wv = tid >> 6;
  const int gw = blockIdx.x * 4 + wv;  // 0..1023
  const float E2 = 7.3890560989306495f;
  const float LN2 = 0.6931471805599453f;
  const bool in1 = (l < 8) | ((l >= 16) & (l < 24));  // r11 | r12 lanes
  const bool in2 = ((l >= 8) & (l < 16)) | ((l >= 24) & (l < 56));
  float acc = 0.f;
  for (int t = 0; t < 8; ++t) {
    int i = gw * 8 + t;
    int off = (((l >> 3) ^ (i & 7)) << 4) + ((2 * l) & 15);
    unsigned int a = *(const unsigned short*)(hs1 + (size_t)i * 128 + off);
    unsigned int b = *(const unsigned short*)(hs2 + (size_t)i * 128 + off);
    float p = fp8d(a & 0xFFu) * fp8d(b & 0xFFu) + fp8d(a >> 8) * fp8d(b >> 8);
    float v = 0.f;
    if (l < 24)
      v = Rp[(size_t)l * NROWS + i];
    else if (l < 56)
      v = R21p[(size_t)(l - 24) * NROWS + i];
    float v1 = in1 ? v : 0.f;
    float v2 = in2 ? v : 0.f;
#pragma unroll
    for (int m = 1; m < 64; m <<= 1) {
      p += __shfl_xor(p, m, 64);
      v1 += __shfl_xor(v1, m, 64);
      v2 += __shfl_xor(v2, m, 64);
    }
    if (l == 0)
      acc += -LN2 * p + 0.5f * (logf(v1 - E2) + logf(v2 - E2));
  }
  __shared__ float wacc[4];
  if (l == 0) wacc[wv] = acc;
  __syncthreads();
  if (tid == 0) partial[blockIdx.x] = wacc[0] + wacc[1] + wacc[2] + wacc[3];
}

__global__ void loss_final(const float* __restrict__ partial, float* __restrict__ outp) {
  const int t = threadIdx.x;
  float v = partial[t] + partial[t + 64] + partial[t + 128] + partial[t + 192];
#pragma unroll
  for (int m = 1; m < 64; m <<= 1) v += __shfl_xor(v, m, 64);
  if (t == 0) outp[0] = v * (1.0f / 8192.0f);
}

// ---------------------------------------------------------------------------
extern "C" void kernel_launch(void* const* d_in, const int* in_sizes, int n_in,
                              void* d_out, int out_size, void* d_ws, size_t ws_size,
                              hipStream_t stream) {
  const float* z1 = (const float*)d_in[0];
  const float* z2 = (const float*)d_in[1];
  const float* w1 = (const float*)d_in[2];
  const float* b1 = (const float*)d_in[3];
  const float* w2 = (const float*)d_in[4];
  const float* b2 = (const float*)d_in[5];
  char* ws = (char*)d_ws;
  unsigned char* hs1 = (unsigned char*)ws;                               // 0..1 MB
  unsigned char* hs2 = (unsigned char*)(ws + (size_t)1 * 1024 * 1024);   // 1..2 MB
  float* Rp = (float*)(ws + (size_t)2 * 1024 * 1024);                    // 768 KB
  float* R21p = (float*)(ws + (size_t)2 * 1024 * 1024 + 768 * 1024);     // 1 MB
  float* partial = (float*)(ws + (size_t)4 * 1024 * 1024);               // 1 KB
  unsigned short* w1b = (unsigned short*)(ws + (size_t)4 * 1024 * 1024 + 64 * 1024);   // 32 KB
  unsigned short* w2b = (unsigned short*)(ws + (size_t)4 * 1024 * 1024 + 128 * 1024);  // 32 KB
  float* outp = (float*)d_out;

  wconv_kernel<<<dim3(16), dim3(256), 0, stream>>>(w1, w2, w1b, w2b);
  proj_kernel<<<dim3(256), dim3(256), 0, stream>>>(z1, z2, w1b, w2b, b1, b2, hs1, hs2);
  gram_kernel<<<dim3(768), dim3(256), 0, stream>>>(hs1, hs2, Rp, R21p);
  loss_kernel<<<dim3(256), dim3(256), 0, stream>>>(hs1, hs2, Rp, R21p, partial);
  loss_final<<<dim3(1), dim3(64), 0, stream>>>(partial, outp);
}

// Round 20
// 61.245 us; speedup vs baseline: 1.1047x; 1.1047x over previous
//
#include <hip/hip_runtime.h>
#include <stdint.h>

typedef __attribute__((ext_vector_type(4))) float f32x4;
typedef __attribute__((ext_vector_type(8))) short short8;
typedef __attribute__((ext_vector_type(8))) int int8v;

#define NROWS 8192
#define SCALE1 0x7F7F7F7F  // 4x E8M0 bytes encoding 2^0 = 1.0

static __device__ __forceinline__ unsigned int f2bf(float f) {
  unsigned int u = __float_as_uint(f);
  return (u + 0x7fffu + ((u >> 16) & 1u)) >> 16;  // RNE
}
static __device__ __forceinline__ float bf2f(unsigned int h) {
  return __uint_as_float(h << 16);
}
static __device__ __forceinline__ float fast_exp2(float x) {
#if __has_builtin(__builtin_amdgcn_exp2f)
  return __builtin_amdgcn_exp2f(x);
#else
  float r;
  asm("v_exp_f32 %0, %1" : "=v"(r) : "v"(x));
  return r;
#endif
}
static __device__ __forceinline__ float fast_expm1(float x) {
  return fast_exp2(x * 1.4426950408889634f) - 1.0f;
}
// f32 -> OCP e4m3fn byte
static __device__ __forceinline__ unsigned f2fp8(float v) {
#if __has_builtin(__builtin_amdgcn_cvt_pk_fp8_f32)
  return (unsigned)__builtin_amdgcn_cvt_pk_fp8_f32(v, v, 0, false) & 0xFFu;
#else
  float a = fabsf(v);
  unsigned sgn = v < 0.f ? 0x80u : 0u;
  if (a > 448.f) a = 448.f;
  if (a < 0.015625f) {
    int q = (int)(a * 512.0f + 0.5f);
    return sgn | (unsigned)q;
  }
  int ex;
  float mant = frexpf(a, &ex);
  int e = ex + 6;
  int m = (int)(mant * 16.0f + 0.5f) - 8;
  if (m == 8) { m = 0; ++e; }
  if (e > 15) { e = 15; m = 7; }
  return sgn | (unsigned)(e << 3) | (unsigned)m;
#endif
}
// OCP e4m3fn byte -> f32
static __device__ __forceinline__ float fp8d(unsigned b) {
  unsigned e = (b >> 3) & 15u, m = b & 7u;
  float v = (e == 0) ? (float)m * 0.001953125f
                     : __uint_as_float(((e + 120u) << 23) | (m << 20));
  return (b & 0x80u) ? -v : v;
}

// hs-fp8 layout: rows of 128 B; 16B chunk c stored at position c ^ (row&7).
// Pre-swizzled global + linear global_load_lds DMA + per-lane swizzled read
// addresses (m201 both-sides pattern). Lane fragment for 16x16x128 MFMA:
// row = l&15, k-bytes = logical chunks {2lh, 2lh+1}.

// ---------------------------------------------------------------------------
// Kernel 1: projection fc2(elu(fc1(z))) + L2-normalize, bf16 MFMA + f32
// epilogue; fp8 e4m3 output rows pre-scaled by sqrt(2*log2 e).
// (r15 verbatim — session-best configuration)
// ---------------------------------------------------------------------------
__global__ __launch_bounds__(256) void proj_kernel(
    const float* __restrict__ z1, const float* __restrict__ z2,
    const float* __restrict__ w1g, const float* __restrict__ b1g,
    const float* __restrict__ w2g, const float* __restrict__ b2g,
    unsigned char* __restrict__ hs1, unsigned char* __restrict__ hs2) {
  __shared__ unsigned short W1[128 * 128];
  __shared__ unsigned short W2[128 * 128];
  __shared__ unsigned short X[64 * 128];
  const int tid = threadIdx.x;
  const int w = tid >> 6, l = tid & 63, l16 = l & 15, lh = l >> 4;
  const int zi = blockIdx.x >> 7, rb = blockIdx.x & 127;
  const float* zg = (zi ? z2 : z1) + (size_t)rb * 64 * 128;
  unsigned char* outp = (zi ? hs2 : hs1) + (size_t)rb * 64 * 128;

  float bias1[8], bias2[8];
#pragma unroll
  for (int nf = 0; nf < 8; ++nf) {
    bias1[nf] = b1g[nf * 16 + l16];
    bias2[nf] = b2g[nf * 16 + l16];
  }

#pragma unroll
  for (int t = 0; t < 16; ++t) {
    int c = tid + t * 256;
    int r = c >> 5, q = c & 31;
    int off = r * 256 + ((((q >> 1) ^ (r & 7)) << 4) | ((q & 1) << 3));
    f32x4 va = *(const f32x4*)&w1g[c * 4];
    f32x4 vb = *(const f32x4*)&w2g[c * 4];
    uint2 pa, pb;
    pa.x = f2bf(va.x) | (f2bf(va.y) << 16);
    pa.y = f2bf(va.z) | (f2bf(va.w) << 16);
    pb.x = f2bf(vb.x) | (f2bf(vb.y) << 16);
    pb.y = f2bf(vb.z) | (f2bf(vb.w) << 16);
    *(uint2*)((char*)W1 + off) = pa;
    *(uint2*)((char*)W2 + off) = pb;
  }
#pragma unroll
  for (int t = 0; t < 8; ++t) {
    int c = tid + t * 256;
    int r = c >> 5, q = c & 31;
    int off = r * 256 + ((((q >> 1) ^ (r & 7)) << 4) | ((q & 1) << 3));
    f32x4 v = *(const f32x4*)&zg[c * 4];
    uint2 p;
    p.x = f2bf(v.x) | (f2bf(v.y) << 16);
    p.y = f2bf(v.z) | (f2bf(v.w) << 16);
    *(uint2*)((char*)X + off) = p;
  }
  __syncthreads();

  const f32x4 ZERO = {0.f, 0.f, 0.f, 0.f};
  const int arow = w * 16 + l16;

  short8 a1[4];
#pragma unroll
  for (int ks = 0; ks < 4; ++ks)
    a1[ks] = *(const short8*)((const char*)X + arow * 256 +
                              ((ks * 64 + lh * 16) ^ ((arow & 7) << 4)));
  f32x4 h[8];
#pragma unroll
  for (int nf = 0; nf < 8; ++nf) {
    const int brow = nf * 16 + l16;
    const char* bp = (const char*)W1 + brow * 256;
    f32x4 c = ZERO;
#pragma unroll
    for (int ks = 0; ks < 4; ++ks) {
      short8 b = *(const short8*)(bp + ((ks * 64 + lh * 16) ^ ((brow & 7) << 4)));
      c = __builtin_amdgcn_mfma_f32_16x16x32_bf16(a1[ks], b, c, 0, 0, 0);
    }
#pragma unroll
    for (int r = 0; r < 4; ++r) {
      float x = c[r] + bias1[nf];
      c[r] = x > 0.f ? x : fast_expm1(x);
    }
    h[nf] = c;
  }
  __syncthreads();

#pragma unroll
  for (int nf = 0; nf < 8; ++nf)
#pragma unroll
    for (int r = 0; r < 4; ++r) {
      int row = w * 16 + lh * 4 + r;
      int c2 = (nf * 16 + l16) * 2;
      int off = row * 256 + ((c2 & ~15) ^ ((row & 7) << 4)) + (c2 & 15);
      *(unsigned short*)((char*)X + off) = (unsigned short)f2bf(h[nf][r]);
    }
  __syncthreads();

  short8 a2[4];
#pragma unroll
  for (int ks = 0; ks < 4; ++ks)
    a2[ks] = *(const short8*)((const char*)X + arow * 256 +
                              ((ks * 64 + lh * 16) ^ ((arow & 7) << 4)));
  f32x4 o[8];
#pragma unroll
  for (int nf = 0; nf < 8; ++nf) {
    const int brow = nf * 16 + l16;
    const char* bp = (const char*)W2 + brow * 256;
    f32x4 c = ZERO;
#pragma unroll
    for (int ks = 0; ks < 4; ++ks) {
      short8 b = *(const short8*)(bp + ((ks * 64 + lh * 16) ^ ((brow & 7) << 4)));
      c = __builtin_amdgcn_mfma_f32_16x16x32_bf16(a2[ks], b, c, 0, 0, 0);
    }
#pragma unroll
    for (int r = 0; r < 4; ++r) c[r] += bias2[nf];
    o[nf] = c;
  }

  float ss[4] = {0.f, 0.f, 0.f, 0.f};
#pragma unroll
  for (int nf = 0; nf < 8; ++nf)
#pragma unroll
    for (int r = 0; r < 4; ++r) ss[r] += o[nf][r] * o[nf][r];
#pragma unroll
  for (int m = 1; m <= 8; m <<= 1)
#pragma unroll
    for (int r = 0; r < 4; ++r) ss[r] += __shfl_xor(ss[r], m, 64);
  float sc[4];
#pragma unroll
  for (int r = 0; r < 4; ++r)
    sc[r] = 1.6986436005760381f / fmaxf(sqrtf(ss[r]), 1e-12f);

#pragma unroll
  for (int nf = 0; nf < 8; ++nf)
#pragma unroll
    for (int r = 0; r < 4; ++r) {
      int row = w * 16 + lh * 4 + r;
      outp[(size_t)row * 128 + ((nf ^ (row & 7)) << 4) + l16] =
          (unsigned char)f2fp8(o[nf][r] * sc[r]);
    }
}

// ---------------------------------------------------------------------------
// Kernel 2: fused Gram + exp2 + row-sum (+ col-sum in pass 2), FP8-MX.
// r15 verbatim (session best: 46.1us gram, 61.2us total). One
// mfma_scale_f32_16x16x128_f8f6f4 (scales=1.0) = full K=128 Gram tile.
// grid 768 = 3 passes x 32 rowblocks(256) x 8 cr(1024), 256 thr, (256,3),
// deferred-exp + setprio, Bbuf[2] 64-col cts + syncthreads.
// ---------------------------------------------------------------------------
#define EXPBLOCK(G, SLOT)                                             \
  {                                                                   \
    float cs = 0.f;                                                   \
    _Pragma("unroll") for (int mf = 0; mf < 4; ++mf)                  \
        _Pragma("unroll") for (int r = 0; r < 4; ++r) {               \
      float e = fast_exp2(cbuf[SLOT][mf][r]);                         \
      rs[mf][r] += e;                                                 \
      if (do_cs) cs += e;                                             \
    }                                                                 \
    if (do_cs) {                                                      \
      cs += __shfl_xor(cs, 16, 64);                                   \
      cs += __shfl_xor(cs, 32, 64);                                   \
      if (lh == 0) csbuf[cur][w][(G)*16 + l16] = cs;                  \
    }                                                                 \
  }

__global__ __launch_bounds__(256, 3) void gram_kernel(
    const unsigned char* __restrict__ hs1, const unsigned char* __restrict__ hs2,
    float* __restrict__ Rp,     // [24][8192] (pass*8+cr) row-sum partials
    float* __restrict__ R21p) { // [32][8192] col-sum partials (pass 2)
  __shared__ __align__(16) unsigned char Bbuf[2][64 * 128];  // 2 x 8KB
  __shared__ float csbuf[2][4][64];

  const int tid = threadIdx.x;
  const int w = tid >> 6, l = tid & 63, l16 = l & 15, lh = l >> 4;
  const int pass = blockIdx.x >> 8;
  const int idx = blockIdx.x & 255;
  const int rb = idx >> 3;  // 32 rowblocks of 256 rows
  const int cr = idx & 7;   // 8 col-ranges of 1024 cols

  const unsigned char* Ag = (pass == 1) ? hs2 : hs1;
  const unsigned char* Bg = (pass == 0) ? hs1 : hs2;
  const char* bbase = (const char*)Bg + (size_t)cr * (1024 * 128);
  const bool do_cs = (pass == 2);

  auto STAGE = [&](int buf, int ct) {
#pragma unroll
    for (int s = 0; s < 2; ++s) {
      const char* src = bbase + (size_t)ct * 8192 + s * 4096 + tid * 16;
      char* dst = (char*)Bbuf[buf] + s * 4096 + w * 1024;  // wave-uniform base
      __builtin_amdgcn_global_load_lds(
          (const __attribute__((address_space(1))) void*)src,
          (__attribute__((address_space(3))) void*)dst, 16, 0, 0);
    }
  };

  STAGE(0, 0);

  // per-lane swizzled 16B-chunk offsets for the 2 halves of a 32B fragment
  const int koff0 = ((2 * lh) ^ (l16 & 7)) << 4;
  const int koff1 = ((2 * lh + 1) ^ (l16 & 7)) << 4;

  int8v af[4];  // 64 rows per wave: 32 VGPRs
  {
    const char* abase = (const char*)Ag + ((size_t)rb * 256 + w * 64) * 128;
#pragma unroll
    for (int mf = 0; mf < 4; ++mf) {
      const char* rp = abase + (mf * 16 + l16) * 128;
      int4 x0 = *(const int4*)(rp + koff0);
      int4 x1 = *(const int4*)(rp + koff1);
      int8v v;
      v[0] = x0.x; v[1] = x0.y; v[2] = x0.z; v[3] = x0.w;
      v[4] = x1.x; v[5] = x1.y; v[6] = x1.z; v[7] = x1.w;
      af[mf] = v;
    }
  }

  float rs[4][4];
#pragma unroll
  for (int mf = 0; mf < 4; ++mf)
#pragma unroll
    for (int r = 0; r < 4; ++r) rs[mf][r] = 0.f;
  const f32x4 ZERO = {0.f, 0.f, 0.f, 0.f};

  __syncthreads();  // tile 0 staged

  for (int ct = 0; ct < 16; ++ct) {
    const int cur = ct & 1;
    if (ct + 1 < 16) STAGE(cur ^ 1, ct + 1);
    if (do_cs && w == 0 && ct > 0) {  // flush prev tile's col-sums (overlaps)
      float v = (csbuf[cur ^ 1][0][l] + csbuf[cur ^ 1][1][l]) +
                (csbuf[cur ^ 1][2][l] + csbuf[cur ^ 1][3][l]);
      R21p[(size_t)rb * NROWS + cr * 1024 + (ct - 1) * 64 + l] = v;
    }
    f32x4 cbuf[2][4];
#pragma unroll
    for (int nf = 0; nf < 4; ++nf) {
      const char* bp = (const char*)Bbuf[cur] + (nf * 16 + l16) * 128;
      int4 b0 = *(const int4*)(bp + koff0);
      int4 b1 = *(const int4*)(bp + koff1);
      int8v bv;
      bv[0] = b0.x; bv[1] = b0.y; bv[2] = b0.z; bv[3] = b0.w;
      bv[4] = b1.x; bv[5] = b1.y; bv[6] = b1.z; bv[7] = b1.w;
      __builtin_amdgcn_s_setprio(1);
#pragma unroll
      for (int mf = 0; mf < 4; ++mf)  // one MFMA = full K=128 dot
        cbuf[nf & 1][mf] = __builtin_amdgcn_mfma_scale_f32_16x16x128_f8f6f4(
            af[mf], bv, ZERO, 0, 0, 0, SCALE1, 0, SCALE1);
      __builtin_amdgcn_s_setprio(0);
      // deferred exp: process PREVIOUS group's C (operands long ready)
      if (nf > 0) EXPBLOCK(nf - 1, (nf ^ 1) & 1);
    }
    EXPBLOCK(3, 1);  // last group's exp
    __syncthreads();
  }
  if (do_cs && w == 0) {  // flush last tile (ct=15 -> buf 1)
    float v = (csbuf[1][0][l] + csbuf[1][1][l]) + (csbuf[1][2][l] + csbuf[1][3][l]);
    R21p[(size_t)rb * NROWS + cr * 1024 + 15 * 64 + l] = v;
  }

  // row-sums: reduce over the 16 col-lanes; C/D row = mf*16 + lh*4 + r [m89]
#pragma unroll
  for (int m = 1; m <= 8; m <<= 1)
#pragma unroll
    for (int mf = 0; mf < 4; ++mf)
#pragma unroll
      for (int r = 0; r < 4; ++r) rs[mf][r] += __shfl_xor(rs[mf][r], m, 64);
  if (l16 == 0) {
    float* base = &Rp[(size_t)(pass * 8 + cr) * NROWS + rb * 256 + w * 64];
#pragma unroll
    for (int mf = 0; mf < 4; ++mf) {
      f32x4 v = {rs[mf][0], rs[mf][1], rs[mf][2], rs[mf][3]};
      *(f32x4*)(base + mf * 16 + lh * 4) = v;
    }
  }
}

// ---------------------------------------------------------------------------
// Kernel 3: merged denom+loss (r15 structure): lane l<24 loads Rp[l][i],
// lanes 24..55 load R21p[l-24][i]; masked wave-reduces give d1,d2.
// ---------------------------------------------------------------------------
__global__ __launch_bounds__(256) void loss_kernel(
    const unsigned char* __restrict__ hs1, const unsigned char* __restrict__ hs2,
    const float* __restrict__ Rp, const float* __restrict__ R21p,
    float* __restrict__ partial) {
  const int tid = threadIdx.x;
  const int l = tid & 63;
  const int wv = tid >> 6;
  const int gw = blockIdx.x * 4 + wv;  // 0..1023
  const float E2 = 7.3890560989306495f;
  const float LN2 = 0.6931471805599453f;
  const bool in1 = (l < 8) | ((l >= 16) & (l < 24));  // r11 | r12 lanes
  const bool in2 = ((l >= 8) & (l < 16)) | ((l >= 24) & (l < 56));
  float acc = 0.f;
  for (int t = 0; t < 8; ++t) {
    int i = gw * 8 + t;
    int off = (((l >> 3) ^ (i & 7)) << 4) + ((2 * l) & 15);
    unsigned int a = *(const unsigned short*)(hs1 + (size_t)i * 128 + off);
    unsigned int b = *(const unsigned short*)(hs2 + (size_t)i * 128 + off);
    float p = fp8d(a & 0xFFu) * fp8d(b & 0xFFu) + fp8d(a >> 8) * fp8d(b >> 8);
    float v = 0.f;
    if (l < 24)
      v = Rp[(size_t)l * NROWS + i];
    else if (l < 56)
      v = R21p[(size_t)(l - 24) * NROWS + i];
    float v1 = in1 ? v : 0.f;
    float v2 = in2 ? v : 0.f;
#pragma unroll
    for (int m = 1; m < 64; m <<= 1) {
      p += __shfl_xor(p, m, 64);
      v1 += __shfl_xor(v1, m, 64);
      v2 += __shfl_xor(v2, m, 64);
    }
    if (l == 0)
      acc += -LN2 * p + 0.5f * (logf(v1 - E2) + logf(v2 - E2));
  }
  __shared__ float wacc[4];
  if (l == 0) wacc[wv] = acc;
  __syncthreads();
  if (tid == 0) partial[blockIdx.x] = wacc[0] + wacc[1] + wacc[2] + wacc[3];
}

__global__ void loss_final(const float* __restrict__ partial, float* __restrict__ outp) {
  const int t = threadIdx.x;
  float v = partial[t] + partial[t + 64] + partial[t + 128] + partial[t + 192];
#pragma unroll
  for (int m = 1; m < 64; m <<= 1) v += __shfl_xor(v, m, 64);
  if (t == 0) outp[0] = v * (1.0f / 8192.0f);
}

// ---------------------------------------------------------------------------
extern "C" void kernel_launch(void* const* d_in, const int* in_sizes, int n_in,
                              void* d_out, int out_size, void* d_ws, size_t ws_size,
                              hipStream_t stream) {
  const float* z1 = (const float*)d_in[0];
  const float* z2 = (const float*)d_in[1];
  const float* w1 = (const float*)d_in[2];
  const float* b1 = (const float*)d_in[3];
  const float* w2 = (const float*)d_in[4];
  const float* b2 = (const float*)d_in[5];
  char* ws = (char*)d_ws;
  unsigned char* hs1 = (unsigned char*)ws;                               // 0..1 MB
  unsigned char* hs2 = (unsigned char*)(ws + (size_t)1 * 1024 * 1024);   // 1..2 MB
  float* Rp = (float*)(ws + (size_t)2 * 1024 * 1024);                    // 768 KB
  float* R21p = (float*)(ws + (size_t)2 * 1024 * 1024 + 768 * 1024);     // 1 MB
  float* partial = (float*)(ws + (size_t)4 * 1024 * 1024);               // 1 KB
  float* outp = (float*)d_out;

  proj_kernel<<<dim3(256), dim3(256), 0, stream>>>(z1, z2, w1, b1, w2, b2, hs1, hs2);
  gram_kernel<<<dim3(768), dim3(256), 0, stream>>>(hs1, hs2, Rp, R21p);
  loss_kernel<<<dim3(256), dim3(256), 0, stream>>>(hs1, hs2, Rp, R21p, partial);
  loss_final<<<dim3(1), dim3(64), 0, stream>>>(partial, outp);
}